// Round 6
// baseline (46560.959 us; speedup 1.0000x reference)
//
#include <hip/hip_runtime.h>

typedef __attribute__((ext_vector_type(4))) float f32x4;
typedef __attribute__((ext_vector_type(8))) short short8;
typedef __attribute__((ext_vector_type(2))) _Float16 half2v;
typedef unsigned int u32;
typedef unsigned short u16;
typedef unsigned long long u64;

#define T_SEQ 4096
#define HDIM  2048
#define GDIM  8192   // 4*H
#define INDIM 512
#define NBLK  256    // recurrence blocks

#if defined(__has_builtin)
#if __has_builtin(__builtin_amdgcn_fdot2)
#define HAS_FDOT2 1
#endif
#endif
#ifndef HAS_FDOT2
#define HAS_FDOT2 0
#endif

__device__ __forceinline__ u16 f2bf(float x) {
  u32 u = __float_as_uint(x);
  return (u16)((u + 0x7fffu + ((u >> 16) & 1u)) >> 16);  // RNE
}
__device__ __forceinline__ u16 f2h(float x) {
  _Float16 h = (_Float16)x;  // RNE
  return __builtin_bit_cast(unsigned short, h);
}
__device__ __forceinline__ float hlo(u32 u) {
  return (float)__builtin_bit_cast(_Float16, (unsigned short)(u & 0xffffu));
}
__device__ __forceinline__ float hhi(u32 u) {
  return (float)__builtin_bit_cast(_Float16, (unsigned short)(u >> 16));
}

// relaxed agent-scope accessors: single sc-bit instruction to the die-level
// coherence point; NO per-access invalidate/writeback (round-4 lesson).
__device__ __forceinline__ int aload(const int* p) {
  return __hip_atomic_load(p, __ATOMIC_RELAXED, __HIP_MEMORY_SCOPE_AGENT);
}
__device__ __forceinline__ void astore(int* p, int v) {
  __hip_atomic_store(p, v, __ATOMIC_RELAXED, __HIP_MEMORY_SCOPE_AGENT);
}
__device__ __forceinline__ u64 aload64(const u64* p) {
  return __hip_atomic_load(p, __ATOMIC_RELAXED, __HIP_MEMORY_SCOPE_AGENT);
}
__device__ __forceinline__ void astoref(float* p, float v) {
  __hip_atomic_store(p, v, __ATOMIC_RELAXED, __HIP_MEMORY_SCOPE_AGENT);
}

// ---------------- prep kernels ----------------
__global__ void k_zero_f32(float* __restrict__ p, int n) {
  int i = blockIdx.x * blockDim.x + threadIdx.x;
  int st = gridDim.x * blockDim.x;
  for (; i < n; i += st) p[i] = 0.f;
}

__global__ void k_bias_sum(const float* __restrict__ a, const float* __restrict__ b,
                           float* __restrict__ o, int n) {
  int i = blockIdx.x * blockDim.x + threadIdx.x;
  if (i < n) o[i] = a[i] + b[i];
}

__global__ void k_cvt_bf16(const float* __restrict__ in, u16* __restrict__ out, int n) {
  int i = blockIdx.x * blockDim.x + threadIdx.x;
  int st = gridDim.x * blockDim.x;
  for (; i < n; i += st) out[i] = f2bf(in[i]);
}

// Pre-pack W_hh (fp32 [8192][2048]) into the per-block striped F16 layout that
// lstm_rec stages to LDS with plain coalesced uint4 copies.
// slot = s*512 + tid: l = slot&63 (lane), r3 = slot>>6, g = r3&3 (k-subgroup),
// q = (r3>>2)&3 (gate), wv = r3>>4 (wave / h-element).
// gate row = q*2048 + bid*8 + wv ; k = l*32 + g*8 .. +8  (8 f16 -> uint4)
__global__ __launch_bounds__(512) void k_prep_whh(const float* __restrict__ w,
                                                  uint4* __restrict__ out) {
  const int bid = blockIdx.x;
  const int tid = threadIdx.x;
#pragma unroll
  for (int s = 0; s < 16; ++s) {
    int slot = s * 512 + tid;
    int l = slot & 63, r3 = slot >> 6;
    int g = r3 & 3, q = (r3 >> 2) & 3, wv = r3 >> 4;
    int grow = q * HDIM + bid * 8 + wv;
    const float* src = w + (size_t)grow * HDIM + l * 32 + g * 8;
    uint4 o;
    o.x = (u32)f2h(src[0]) | ((u32)f2h(src[1]) << 16);
    o.y = (u32)f2h(src[2]) | ((u32)f2h(src[3]) << 16);
    o.z = (u32)f2h(src[4]) | ((u32)f2h(src[5]) << 16);
    o.w = (u32)f2h(src[6]) | ((u32)f2h(src[7]) << 16);
    out[((size_t)bid * 16 + s) * 512 + tid] = o;
  }
}

// ---------------- bf16 MFMA GEMM:  C[M,N] = A[M,K] * B[N,K]^T + bias[N] ----------------
template <bool AF32>
__global__ __launch_bounds__(256) void gemm_bt_bias(
    const void* __restrict__ Av, const u16* __restrict__ B,
    const float* __restrict__ bias, float* __restrict__ C,
    int M, int N, int K)
{
  __shared__ u16 As[128 * 64];
  __shared__ u16 Bs[128 * 64];
  const int tid = threadIdx.x;
  const int m0 = blockIdx.y * 128;
  const int n0 = blockIdx.x * 128;
  const int w = tid >> 6;
  const int lane = tid & 63;
  const int wm = (w >> 1) * 64, wn = (w & 1) * 64;
  const int lr = lane & 15, lk = lane >> 4;

  f32x4 acc[4][4];
  f32x4 zero = {0.f, 0.f, 0.f, 0.f};
#pragma unroll
  for (int i = 0; i < 4; ++i)
#pragma unroll
    for (int j = 0; j < 4; ++j) acc[i][j] = zero;

  const int r = tid >> 1;           // 0..127 (tile row)
  const int sbase = (tid & 1) * 4;  // slot base (each slot = 8 bf16 = 16B)

  for (int kt = 0; kt < K; kt += 64) {
    uint4 va[4], vb[4];
#pragma unroll
    for (int s = 0; s < 4; ++s) {
      if constexpr (AF32) {
        const float* ga = (const float*)Av + (size_t)(m0 + r) * K + kt + (sbase + s) * 8;
        float4 f0 = *reinterpret_cast<const float4*>(ga);
        float4 f1 = *reinterpret_cast<const float4*>(ga + 4);
        va[s].x = (u32)f2bf(f0.x) | ((u32)f2bf(f0.y) << 16);
        va[s].y = (u32)f2bf(f0.z) | ((u32)f2bf(f0.w) << 16);
        va[s].z = (u32)f2bf(f1.x) | ((u32)f2bf(f1.y) << 16);
        va[s].w = (u32)f2bf(f1.z) | ((u32)f2bf(f1.w) << 16);
      } else {
        const u16* ga = (const u16*)Av + (size_t)(m0 + r) * K + kt + (sbase + s) * 8;
        va[s] = *reinterpret_cast<const uint4*>(ga);
      }
      const u16* gb = B + (size_t)(n0 + r) * K + kt + (sbase + s) * 8;
      vb[s] = *reinterpret_cast<const uint4*>(gb);
    }
    __syncthreads();  // previous iter's reads done before overwrite
#pragma unroll
    for (int s = 0; s < 4; ++s) {
      int ps = (sbase + s) ^ (r & 7);
      *reinterpret_cast<uint4*>(&As[r * 64 + ps * 8]) = va[s];
      *reinterpret_cast<uint4*>(&Bs[r * 64 + ps * 8]) = vb[s];
    }
    __syncthreads();
#pragma unroll
    for (int k32 = 0; k32 < 2; ++k32) {
      short8 af[4], bg[4];
#pragma unroll
      for (int i = 0; i < 4; ++i) {
        int arow = wm + i * 16 + lr;
        int aslot = (k32 * 4 + lk) ^ (arow & 7);
        af[i] = *reinterpret_cast<const short8*>(&As[arow * 64 + aslot * 8]);
        int brow = wn + i * 16 + lr;
        int bslot = (k32 * 4 + lk) ^ (brow & 7);
        bg[i] = *reinterpret_cast<const short8*>(&Bs[brow * 64 + bslot * 8]);
      }
#pragma unroll
      for (int i = 0; i < 4; ++i)
#pragma unroll
        for (int j = 0; j < 4; ++j)
          acc[i][j] = __builtin_amdgcn_mfma_f32_16x16x32_bf16(af[i], bg[j], acc[i][j], 0, 0, 0);
    }
  }

  // epilogue: C/D layout col = lane&15, row = (lane>>4)*4 + reg  [m89-verified]
#pragma unroll
  for (int j = 0; j < 4; ++j) {
    int gcol = n0 + wn + j * 16 + lr;
    float bv = bias[gcol];
#pragma unroll
    for (int i = 0; i < 4; ++i) {
      int grow = m0 + wm + i * 16 + lk * 4;
#pragma unroll
      for (int rr = 0; rr < 4; ++rr)
        C[(size_t)(grow + rr) * N + gcol] = acc[i][j][rr] + bv;
    }
  }
}

// ---------------- persistent LSTM recurrence, LDS weights + direct poll ----
// 256 blocks x 512 threads (8 waves). Wave wv owns h-element bid*8+wv and its
// 4 gate rows. Weights f16 in LDS (128 KiB). Per step:
//  - each thread polls ITS OWN producer's flag (flags[tid>>1], packed int[256]
//    -> wave-coalesced ~2-3 line requests/sweep) with relaxed loads; no hub,
//    no epoch. Compiler reorder of the h load above the poll is blocked by the
//    memory-clobber asm; HW order by the poll's control dependence.
//  - h chunk loaded via relaxed-agent u64 atomics (coherence point, fresh),
//    staged to swizzled LDS; B2; f16 dot (v_dot2_f32_f16 when available);
//    64-lane butterfly; lane 0 gates + write-through h store.
//  - B3 (implicit vmcnt(0) drain per wave) then tid0 publishes flags[bid]=t+1.
__global__ __launch_bounds__(512, 1) void lstm_rec(
    const float* __restrict__ gx,    // [T][8192] input contribution (+biases)
    const uint4* __restrict__ wp,    // pre-packed f16 weights [256][16][512] uint4
    float* __restrict__ hhist,       // rows of 2048 floats, row 0 pre-zeroed
    int* __restrict__ flags,         // int[NBLK] packed, pre-zeroed
    int hmask, int T)
{
  __shared__ uint4 wlds[16 * 512];   // 128 KiB f16 weights
  __shared__ float4 hT[512];         // 8 KiB swizzled h row
  const int tid = threadIdx.x;
  const int bid = blockIdx.x;
  const int wv = tid >> 6;  // wave -> h element bid*8+wv
  const int l = tid & 63;

  // stage weights once (coalesced; B2 of first iteration orders writes vs reads)
#pragma unroll
  for (int s = 0; s < 16; ++s)
    wlds[s * 512 + tid] = wp[((size_t)bid * 16 + s) * 512 + tid];

  const int* myflag = &flags[tid >> 1];  // producer block of h[4*tid .. +4)
  float c = 0.f;                         // cell state (lane 0 of each wave)

  for (int t = 0; t < T; ++t) {
    // gx prefetch (cached load, independent of h[t]; overlaps the poll)
    float gv = 0.f;
    if (l < 4) gv = gx[(size_t)t * GDIM + l * HDIM + bid * 8 + wv];

    // wait for MY chunk's producer only
    while (aload(myflag) < t) __builtin_amdgcn_s_sleep(1);
    asm volatile("" ::: "memory");  // no compiler hoist of h load above poll

    // stage my h chunk into LDS (relaxed-agent 8B loads -> always fresh)
    {
      const u64* hsrc = (const u64*)(hhist + (size_t)(t & hmask) * HDIM);
      u64 d0 = aload64(&hsrc[tid * 2]);
      u64 d1 = aload64(&hsrc[tid * 2 + 1]);
      float4 hv;
      hv.x = __uint_as_float((u32)d0);
      hv.y = __uint_as_float((u32)(d0 >> 32));
      hv.z = __uint_as_float((u32)d1);
      hv.w = __uint_as_float((u32)(d1 >> 32));
      int G2 = tid & 7, sb = tid >> 3;
      hT[G2 * 64 + (sb ^ ((G2 * 9) & 63))] = hv;
    }
    __syncthreads();  // B2: h staged (also orders initial weight staging)

    float a0 = 0.f, a1 = 0.f, a2 = 0.f, a3 = 0.f;
#pragma unroll
    for (int g = 0; g < 4; ++g) {
      const int G0 = g * 2, G1 = g * 2 + 1;
      float4 h0 = hT[G0 * 64 + (l ^ ((G0 * 9) & 63))];
      float4 h1 = hT[G1 * 64 + (l ^ ((G1 * 9) & 63))];
      uint4 w0 = wlds[(wv * 16 + 0 * 4 + g) * 64 + l];
      uint4 w1 = wlds[(wv * 16 + 1 * 4 + g) * 64 + l];
      uint4 w2 = wlds[(wv * 16 + 2 * 4 + g) * 64 + l];
      uint4 w3 = wlds[(wv * 16 + 3 * 4 + g) * 64 + l];
#if HAS_FDOT2
      half2v p0, p1, p2, p3;
      p0[0] = (_Float16)h0.x; p0[1] = (_Float16)h0.y;
      p1[0] = (_Float16)h0.z; p1[1] = (_Float16)h0.w;
      p2[0] = (_Float16)h1.x; p2[1] = (_Float16)h1.y;
      p3[0] = (_Float16)h1.z; p3[1] = (_Float16)h1.w;
#define FD2(wu, pp, acc) __builtin_amdgcn_fdot2(__builtin_bit_cast(half2v, (wu)), (pp), (acc), false)
      a0 = FD2(w0.x, p0, FD2(w0.y, p1, FD2(w0.z, p2, FD2(w0.w, p3, a0))));
      a1 = FD2(w1.x, p0, FD2(w1.y, p1, FD2(w1.z, p2, FD2(w1.w, p3, a1))));
      a2 = FD2(w2.x, p0, FD2(w2.y, p1, FD2(w2.z, p2, FD2(w2.w, p3, a2))));
      a3 = FD2(w3.x, p0, FD2(w3.y, p1, FD2(w3.z, p2, FD2(w3.w, p3, a3))));
#undef FD2
#else
      a0 += hlo(w0.x) * h0.x + hhi(w0.x) * h0.y + hlo(w0.y) * h0.z + hhi(w0.y) * h0.w +
            hlo(w0.z) * h1.x + hhi(w0.z) * h1.y + hlo(w0.w) * h1.z + hhi(w0.w) * h1.w;
      a1 += hlo(w1.x) * h0.x + hhi(w1.x) * h0.y + hlo(w1.y) * h0.z + hhi(w1.y) * h0.w +
            hlo(w1.z) * h1.x + hhi(w1.z) * h1.y + hlo(w1.w) * h1.z + hhi(w1.w) * h1.w;
      a2 += hlo(w2.x) * h0.x + hhi(w2.x) * h0.y + hlo(w2.y) * h0.z + hhi(w2.y) * h0.w +
            hlo(w2.z) * h1.x + hhi(w2.z) * h1.y + hlo(w2.w) * h1.z + hhi(w2.w) * h1.w;
      a3 += hlo(w3.x) * h0.x + hhi(w3.x) * h0.y + hlo(w3.y) * h0.z + hhi(w3.y) * h0.w +
            hlo(w3.z) * h1.x + hhi(w3.z) * h1.y + hlo(w3.w) * h1.z + hhi(w3.w) * h1.w;
#endif
    }
    // 64-lane butterfly: all lanes end with the 4 gate sums
#pragma unroll
    for (int m = 32; m >= 1; m >>= 1) {
      a0 += __shfl_xor(a0, m);
      a1 += __shfl_xor(a1, m);
      a2 += __shfl_xor(a2, m);
      a3 += __shfl_xor(a3, m);
    }
    float g0 = __shfl(gv, 0), g1 = __shfl(gv, 1), g2 = __shfl(gv, 2), g3 = __shfl(gv, 3);
    if (l == 0) {
      float pi = a0 + g0, pf = a1 + g1, pg = a2 + g2, po = a3 + g3;
      float i_ = 1.f / (1.f + expf(-pi));
      float f_ = 1.f / (1.f + expf(-pf));
      float gg = tanhf(pg);
      float o_ = 1.f / (1.f + expf(-po));
      c = f_ * c + i_ * gg;
      // write-through store: at coherence point once this wave's vmcnt drains
      astoref(&hhist[(size_t)((t + 1) & hmask) * HDIM + bid * 8 + wv], o_ * tanhf(c));
    }
    __syncthreads();  // B3: every wave drained vmcnt(0) before s_barrier
    if (tid == 0) astore(&flags[bid], t + 1);
  }
}

// ---------------- heads: two 2048-dots ----------------
__global__ void k_heads(const float* __restrict__ h, const float* __restrict__ wt,
                        const float* __restrict__ bt, const float* __restrict__ wf,
                        const float* __restrict__ bfp, float* __restrict__ out) {
  int tid = threadIdx.x;  // 256
  float st = 0.f, sf = 0.f;
  for (int i = tid; i < HDIM; i += 256) {
    float hv = h[i];
    st += hv * wt[i];
    sf += hv * wf[i];
  }
#pragma unroll
  for (int m = 32; m >= 1; m >>= 1) {
    st += __shfl_xor(st, m, 64);
    sf += __shfl_xor(sf, m, 64);
  }
  __shared__ float ra[4], rb[4];
  if ((tid & 63) == 0) { ra[tid >> 6] = st; rb[tid >> 6] = sf; }
  __syncthreads();
  if (tid == 0) {
    out[0] = ra[0] + ra[1] + ra[2] + ra[3] + bt[0];
    out[1] = rb[0] + rb[1] + rb[2] + rb[3] + bfp[0];
  }
}

// ---------------- launch ----------------
extern "C" void kernel_launch(void* const* d_in, const int* in_sizes, int n_in,
                              void* d_out, int out_size, void* d_ws, size_t ws_size,
                              hipStream_t stream) {
  const float* x     = (const float*)d_in[0];
  const float* w_ih0 = (const float*)d_in[1];
  const float* w_hh0 = (const float*)d_in[2];
  const float* b_ih0 = (const float*)d_in[3];
  const float* b_hh0 = (const float*)d_in[4];
  const float* w_ih1 = (const float*)d_in[5];
  const float* w_hh1 = (const float*)d_in[6];
  const float* b_ih1 = (const float*)d_in[7];
  const float* b_hh1 = (const float*)d_in[8];
  const float* w_t   = (const float*)d_in[9];
  const float* b_t   = (const float*)d_in[10];
  const float* w_f   = (const float*)d_in[11];
  const float* b_f   = (const float*)d_in[12];

  // workspace layout (bytes), total ~236.2 MiB (known-good budget)
  char* p = (char*)d_ws;
  float* gx    = (float*)(p);                 // 134,217,728
  float* hs0f  = (float*)(p + 134217728);     // 4097*2048*4 = 33,562,624
  u16*   xb    = (u16*)  (p + 167780352);     // 4,194,304
  u16*   wb0   = (u16*)  (p + 171974656);     // 8,388,608
  u16*   wb1   = (u16*)  (p + 180363264);     // 33,554,432
  uint4* wprep = (uint4*)(p + 213917696);     // 33,554,432 (reused per layer)
  float* h1r   = (float*)(p + 247472128);     // 4*2048*4 = 32,768 (depth-4 ring)
  float* bias0 = (float*)(p + 247504896);     // 32,768
  float* bias1 = (float*)(p + 247537664);     // 32,768
  int*   flags0= (int*)  (p + 247570432);     // packed int[256] (32 KiB slot)
  int*   flags1= (int*)  (p + 247603200);     // packed int[256] (32 KiB slot)

  // init (re-run every launch => deterministic graph replay)
  k_zero_f32<<<8, 256, 0, stream>>>(hs0f, HDIM);        // h0 row 0 = 0
  k_zero_f32<<<32, 256, 0, stream>>>(h1r, 4 * HDIM);    // layer-1 ring = 0
  k_zero_f32<<<64, 256, 0, stream>>>((float*)flags0, 2 * 8192 + 64);  // both flag slots
  k_bias_sum<<<GDIM / 256, 256, 0, stream>>>(b_ih0, b_hh0, bias0, GDIM);
  k_bias_sum<<<GDIM / 256, 256, 0, stream>>>(b_ih1, b_hh1, bias1, GDIM);
  k_cvt_bf16<<<1024, 256, 0, stream>>>(x, xb, T_SEQ * INDIM);
  k_cvt_bf16<<<1024, 256, 0, stream>>>(w_ih0, wb0, GDIM * INDIM);
  k_cvt_bf16<<<2048, 256, 0, stream>>>(w_ih1, wb1, GDIM * HDIM);

  // layer 0
  k_prep_whh<<<NBLK, 512, 0, stream>>>(w_hh0, wprep);
  gemm_bt_bias<false><<<dim3(GDIM / 128, T_SEQ / 128), 256, 0, stream>>>(
      xb, wb0, bias0, gx, T_SEQ, GDIM, INDIM);
  lstm_rec<<<NBLK, 512, 0, stream>>>(gx, wprep, hs0f, flags0, 0x7fffffff, T_SEQ);

  // layer 1 (A = hs0 fp32 rows 1..T, converted in GEMM staging)
  gemm_bt_bias<true><<<dim3(GDIM / 128, T_SEQ / 128), 256, 0, stream>>>(
      hs0f + HDIM, wb1, bias1, gx, T_SEQ, GDIM, HDIM);
  k_prep_whh<<<NBLK, 512, 0, stream>>>(w_hh1, wprep);
  lstm_rec<<<NBLK, 512, 0, stream>>>(gx, wprep, h1r, flags1, 3, T_SEQ);

  // heads on h1[T] (ring row T&3 == 0)
  k_heads<<<1, 256, 0, stream>>>(h1r + (size_t)(T_SEQ & 3) * HDIM, w_t, b_t, w_f, b_f,
                                 (float*)d_out);
}

// Round 8
// 29008.118 us; speedup vs baseline: 1.6051x; 1.6051x over previous
//
#include <hip/hip_runtime.h>

typedef __attribute__((ext_vector_type(4))) float f32x4;
typedef __attribute__((ext_vector_type(8))) short short8;
typedef __attribute__((ext_vector_type(2))) _Float16 half2v;
typedef unsigned int u32;
typedef unsigned short u16;
typedef unsigned long long u64;

#define T_SEQ 4096
#define HDIM  2048
#define GDIM  8192   // 4*H
#define INDIM 512
#define NBLK  256    // recurrence blocks
#define FLAG_STRIDE 32  // ints -> 128B per flag line (spread; R5-proven)

#if defined(__has_builtin)
#if __has_builtin(__builtin_amdgcn_fdot2)
#define HAS_FDOT2 1
#endif
#endif
#ifndef HAS_FDOT2
#define HAS_FDOT2 0
#endif

__device__ __forceinline__ u16 f2bf(float x) {
  u32 u = __float_as_uint(x);
  return (u16)((u + 0x7fffu + ((u >> 16) & 1u)) >> 16);  // RNE
}
__device__ __forceinline__ u16 f2h(float x) {
  _Float16 h = (_Float16)x;  // RNE
  return __builtin_bit_cast(unsigned short, h);
}
__device__ __forceinline__ float hlo(u32 u) {
  return (float)__builtin_bit_cast(_Float16, (unsigned short)(u & 0xffffu));
}
__device__ __forceinline__ float hhi(u32 u) {
  return (float)__builtin_bit_cast(_Float16, (unsigned short)(u >> 16));
}

// relaxed agent-scope accessors (single sc-bit op to coherence point, no
// invalidate/writeback). RULE (round-6 lesson): spin-polls must be
// same-address-per-wave / few addresses device-wide.
__device__ __forceinline__ int aload(const int* p) {
  return __hip_atomic_load(p, __ATOMIC_RELAXED, __HIP_MEMORY_SCOPE_AGENT);
}
__device__ __forceinline__ void astore(int* p, int v) {
  __hip_atomic_store(p, v, __ATOMIC_RELAXED, __HIP_MEMORY_SCOPE_AGENT);
}
__device__ __forceinline__ u64 aload64(const u64* p) {
  return __hip_atomic_load(p, __ATOMIC_RELAXED, __HIP_MEMORY_SCOPE_AGENT);
}
__device__ __forceinline__ void astoref(float* p, float v) {
  __hip_atomic_store(p, v, __ATOMIC_RELAXED, __HIP_MEMORY_SCOPE_AGENT);
}

// ---------------- prep kernels ----------------
__global__ void k_zero_f32(float* __restrict__ p, int n) {
  int i = blockIdx.x * blockDim.x + threadIdx.x;
  int st = gridDim.x * blockDim.x;
  for (; i < n; i += st) p[i] = 0.f;
}

__global__ void k_bias_sum(const float* __restrict__ a, const float* __restrict__ b,
                           float* __restrict__ o, int n) {
  int i = blockIdx.x * blockDim.x + threadIdx.x;
  if (i < n) o[i] = a[i] + b[i];
}

__global__ void k_cvt_bf16(const float* __restrict__ in, u16* __restrict__ out, int n) {
  int i = blockIdx.x * blockDim.x + threadIdx.x;
  int st = gridDim.x * blockDim.x;
  for (; i < n; i += st) out[i] = f2bf(in[i]);
}

// Pre-pack W_hh (fp32 [8192][2048]) into per-block striped f16 layout (R6-proven).
// slot = s*512 + tid: l = slot&63 (lane), r3 = slot>>6, g = r3&3 (k-subgroup),
// q = (r3>>2)&3 (gate), wv = r3>>4 (wave / h-element).
// gate row = q*2048 + bid*8 + wv ; k = l*32 + g*8 .. +8  (8 f16 -> uint4)
__global__ __launch_bounds__(512) void k_prep_whh(const float* __restrict__ w,
                                                  uint4* __restrict__ out) {
  const int bid = blockIdx.x;
  const int tid = threadIdx.x;
#pragma unroll
  for (int s = 0; s < 16; ++s) {
    int slot = s * 512 + tid;
    int l = slot & 63, r3 = slot >> 6;
    int g = r3 & 3, q = (r3 >> 2) & 3, wv = r3 >> 4;
    int grow = q * HDIM + bid * 8 + wv;
    const float* src = w + (size_t)grow * HDIM + l * 32 + g * 8;
    uint4 o;
    o.x = (u32)f2h(src[0]) | ((u32)f2h(src[1]) << 16);
    o.y = (u32)f2h(src[2]) | ((u32)f2h(src[3]) << 16);
    o.z = (u32)f2h(src[4]) | ((u32)f2h(src[5]) << 16);
    o.w = (u32)f2h(src[6]) | ((u32)f2h(src[7]) << 16);
    out[((size_t)bid * 16 + s) * 512 + tid] = o;
  }
}

// ---------------- bf16 MFMA GEMM:  C[M,N] = A[M,K] * B[N,K]^T + bias[N] ----------------
template <bool AF32>
__global__ __launch_bounds__(256) void gemm_bt_bias(
    const void* __restrict__ Av, const u16* __restrict__ B,
    const float* __restrict__ bias, float* __restrict__ C,
    int M, int N, int K)
{
  __shared__ u16 As[128 * 64];
  __shared__ u16 Bs[128 * 64];
  const int tid = threadIdx.x;
  const int m0 = blockIdx.y * 128;
  const int n0 = blockIdx.x * 128;
  const int w = tid >> 6;
  const int lane = tid & 63;
  const int wm = (w >> 1) * 64, wn = (w & 1) * 64;
  const int lr = lane & 15, lk = lane >> 4;

  f32x4 acc[4][4];
  f32x4 zero = {0.f, 0.f, 0.f, 0.f};
#pragma unroll
  for (int i = 0; i < 4; ++i)
#pragma unroll
    for (int j = 0; j < 4; ++j) acc[i][j] = zero;

  const int r = tid >> 1;           // 0..127 (tile row)
  const int sbase = (tid & 1) * 4;  // slot base (each slot = 8 bf16 = 16B)

  for (int kt = 0; kt < K; kt += 64) {
    uint4 va[4], vb[4];
#pragma unroll
    for (int s = 0; s < 4; ++s) {
      if constexpr (AF32) {
        const float* ga = (const float*)Av + (size_t)(m0 + r) * K + kt + (sbase + s) * 8;
        float4 f0 = *reinterpret_cast<const float4*>(ga);
        float4 f1 = *reinterpret_cast<const float4*>(ga + 4);
        va[s].x = (u32)f2bf(f0.x) | ((u32)f2bf(f0.y) << 16);
        va[s].y = (u32)f2bf(f0.z) | ((u32)f2bf(f0.w) << 16);
        va[s].z = (u32)f2bf(f1.x) | ((u32)f2bf(f1.y) << 16);
        va[s].w = (u32)f2bf(f1.z) | ((u32)f2bf(f1.w) << 16);
      } else {
        const u16* ga = (const u16*)Av + (size_t)(m0 + r) * K + kt + (sbase + s) * 8;
        va[s] = *reinterpret_cast<const uint4*>(ga);
      }
      const u16* gb = B + (size_t)(n0 + r) * K + kt + (sbase + s) * 8;
      vb[s] = *reinterpret_cast<const uint4*>(gb);
    }
    __syncthreads();  // previous iter's reads done before overwrite
#pragma unroll
    for (int s = 0; s < 4; ++s) {
      int ps = (sbase + s) ^ (r & 7);
      *reinterpret_cast<uint4*>(&As[r * 64 + ps * 8]) = va[s];
      *reinterpret_cast<uint4*>(&Bs[r * 64 + ps * 8]) = vb[s];
    }
    __syncthreads();
#pragma unroll
    for (int k32 = 0; k32 < 2; ++k32) {
      short8 af[4], bg[4];
#pragma unroll
      for (int i = 0; i < 4; ++i) {
        int arow = wm + i * 16 + lr;
        int aslot = (k32 * 4 + lk) ^ (arow & 7);
        af[i] = *reinterpret_cast<const short8*>(&As[arow * 64 + aslot * 8]);
        int brow = wn + i * 16 + lr;
        int bslot = (k32 * 4 + lk) ^ (brow & 7);
        bg[i] = *reinterpret_cast<const short8*>(&Bs[brow * 64 + bslot * 8]);
      }
#pragma unroll
      for (int i = 0; i < 4; ++i)
#pragma unroll
        for (int j = 0; j < 4; ++j)
          acc[i][j] = __builtin_amdgcn_mfma_f32_16x16x32_bf16(af[i], bg[j], acc[i][j], 0, 0, 0);
    }
  }

  // epilogue: C/D layout col = lane&15, row = (lane>>4)*4 + reg  [m89-verified]
#pragma unroll
  for (int j = 0; j < 4; ++j) {
    int gcol = n0 + wn + j * 16 + lr;
    float bv = bias[gcol];
#pragma unroll
    for (int i = 0; i < 4; ++i) {
      int grow = m0 + wm + i * 16 + lk * 4;
#pragma unroll
      for (int rr = 0; rr < 4; ++rr)
        C[(size_t)(grow + rr) * N + gcol] = acc[i][j][rr] + bv;
    }
  }
}

// ---------------- persistent LSTM recurrence ----------------
// R5-proven structure: 256 blocks x 512 threads (8 waves), weights f16 in LDS
// (128 KiB), hub sync (block0 wave0 polls 256 spread flags -> publishes single
// epoch cell; other blocks' wave0 polls epoch; B1 releases all waves), aload64
// h staging to swizzled LDS, libm gates, write-through h store, B3 + flag.
// R6-proven dot: f16 fdot2. NEW (single isolated change): the 16 weight
// ds_read_b128 are issued BEFORE the poll into registers, pinned with R2's
// scalar "+v" asm idiom, taking them off the post-barrier critical path.
__global__ __launch_bounds__(512, 1) void lstm_rec(
    const float* __restrict__ gx,    // [T][8192] input contribution (+biases)
    const uint4* __restrict__ wp,    // pre-packed f16 weights [256][16][512]
    float* __restrict__ hhist,       // rows of 2048 floats, row 0 pre-zeroed
    int* __restrict__ flags,         // [NBLK*FLAG_STRIDE] spread, pre-zeroed
    int* __restrict__ epoch,         // one cell, pre-zeroed
    int hmask, int T)
{
  __shared__ uint4 wlds[16 * 512];   // 128 KiB f16 weights
  __shared__ float4 hT[512];         // 8 KiB swizzled h row
  const int tid = threadIdx.x;
  const int bid = blockIdx.x;
  const int wv = tid >> 6;  // wave -> h element bid*8+wv
  const int l = tid & 63;

  // stage weights once (coalesced)
#pragma unroll
  for (int s = 0; s < 16; ++s)
    wlds[s * 512 + tid] = wp[((size_t)bid * 16 + s) * 512 + tid];
  __syncthreads();  // B0: wlds complete before the pre-poll prefetch reads it

  float c = 0.f;  // cell state (lane 0 of each wave)

  for (int t = 0; t < T; ++t) {
    // weight prefetch into registers (overlaps the poll; R2-proven scalar pins)
    uint4 wr[16];
#pragma unroll
    for (int s = 0; s < 16; ++s) wr[s] = wlds[(wv * 16 + s) * 64 + l];
#pragma unroll
    for (int s = 0; s < 16; ++s)
      asm volatile("" : "+v"(wr[s].x), "+v"(wr[s].y), "+v"(wr[s].z), "+v"(wr[s].w));

    // gx prefetch (cached load, independent of h[t]; overlaps the poll)
    float gv = 0.f;
    if (l < 4) gv = gx[(size_t)t * GDIM + l * HDIM + bid * 8 + wv];

    // ---- wait for h[t] (R5 verbatim) ----
    if (wv == 0) {
      if (bid == 0) {
        const int* f0 = &flags[(l * 4 + 0) * FLAG_STRIDE];
        const int* f1 = &flags[(l * 4 + 1) * FLAG_STRIDE];
        const int* f2 = &flags[(l * 4 + 2) * FLAG_STRIDE];
        const int* f3 = &flags[(l * 4 + 3) * FLAG_STRIDE];
        while (true) {
          int m0 = min(min(aload(f0), aload(f1)), min(aload(f2), aload(f3)));
          if (__all(m0 >= t)) break;
          __builtin_amdgcn_s_sleep(1);
        }
        if (l == 0) astore(epoch, t);
      } else {
        while (aload(epoch) < t) __builtin_amdgcn_s_sleep(1);
      }
    }
    __syncthreads();  // B1: h[t] globally ready

    // stage h[t] into LDS (relaxed-agent 8B loads -> coherence point, fresh)
    {
      const u64* hsrc = (const u64*)(hhist + (size_t)(t & hmask) * HDIM);
      u64 d0 = aload64(&hsrc[tid * 2]);
      u64 d1 = aload64(&hsrc[tid * 2 + 1]);
      float4 hv;
      hv.x = __uint_as_float((u32)d0);
      hv.y = __uint_as_float((u32)(d0 >> 32));
      hv.z = __uint_as_float((u32)d1);
      hv.w = __uint_as_float((u32)(d1 >> 32));
      int G2 = tid & 7, sb = tid >> 3;
      hT[G2 * 64 + (sb ^ ((G2 * 9) & 63))] = hv;
    }
    __syncthreads();  // B2: h staged

    // dot: 8 hT reads + fdot2 against prefetched weights
    float a0 = 0.f, a1 = 0.f, a2 = 0.f, a3 = 0.f;
#pragma unroll
    for (int g = 0; g < 4; ++g) {
      const int G0 = g * 2, G1 = g * 2 + 1;
      float4 h0 = hT[G0 * 64 + (l ^ ((G0 * 9) & 63))];
      float4 h1 = hT[G1 * 64 + (l ^ ((G1 * 9) & 63))];
#if HAS_FDOT2
      half2v p0, p1, p2, p3;
      p0[0] = (_Float16)h0.x; p0[1] = (_Float16)h0.y;
      p1[0] = (_Float16)h0.z; p1[1] = (_Float16)h0.w;
      p2[0] = (_Float16)h1.x; p2[1] = (_Float16)h1.y;
      p3[0] = (_Float16)h1.z; p3[1] = (_Float16)h1.w;
#define FD2(wu, pp, acc) __builtin_amdgcn_fdot2(__builtin_bit_cast(half2v, (wu)), (pp), (acc), false)
      a0 = FD2(wr[0 + g].x, p0, FD2(wr[0 + g].y, p1, FD2(wr[0 + g].z, p2, FD2(wr[0 + g].w, p3, a0))));
      a1 = FD2(wr[4 + g].x, p0, FD2(wr[4 + g].y, p1, FD2(wr[4 + g].z, p2, FD2(wr[4 + g].w, p3, a1))));
      a2 = FD2(wr[8 + g].x, p0, FD2(wr[8 + g].y, p1, FD2(wr[8 + g].z, p2, FD2(wr[8 + g].w, p3, a2))));
      a3 = FD2(wr[12 + g].x, p0, FD2(wr[12 + g].y, p1, FD2(wr[12 + g].z, p2, FD2(wr[12 + g].w, p3, a3))));
#undef FD2
#else
      a0 += hlo(wr[0 + g].x) * h0.x + hhi(wr[0 + g].x) * h0.y + hlo(wr[0 + g].y) * h0.z + hhi(wr[0 + g].y) * h0.w +
            hlo(wr[0 + g].z) * h1.x + hhi(wr[0 + g].z) * h1.y + hlo(wr[0 + g].w) * h1.z + hhi(wr[0 + g].w) * h1.w;
      a1 += hlo(wr[4 + g].x) * h0.x + hhi(wr[4 + g].x) * h0.y + hlo(wr[4 + g].y) * h0.z + hhi(wr[4 + g].y) * h0.w +
            hlo(wr[4 + g].z) * h1.x + hhi(wr[4 + g].z) * h1.y + hlo(wr[4 + g].w) * h1.z + hhi(wr[4 + g].w) * h1.w;
      a2 += hlo(wr[8 + g].x) * h0.x + hhi(wr[8 + g].x) * h0.y + hlo(wr[8 + g].y) * h0.z + hhi(wr[8 + g].y) * h0.w +
            hlo(wr[8 + g].z) * h1.x + hhi(wr[8 + g].z) * h1.y + hlo(wr[8 + g].w) * h1.z + hhi(wr[8 + g].w) * h1.w;
      a3 += hlo(wr[12 + g].x) * h0.x + hhi(wr[12 + g].x) * h0.y + hlo(wr[12 + g].y) * h0.z + hhi(wr[12 + g].y) * h0.w +
            hlo(wr[12 + g].z) * h1.x + hhi(wr[12 + g].z) * h1.y + hlo(wr[12 + g].w) * h1.z + hhi(wr[12 + g].w) * h1.w;
#endif
    }
    // 64-lane butterfly: all lanes end with the 4 gate sums
#pragma unroll
    for (int m = 32; m >= 1; m >>= 1) {
      a0 += __shfl_xor(a0, m);
      a1 += __shfl_xor(a1, m);
      a2 += __shfl_xor(a2, m);
      a3 += __shfl_xor(a3, m);
    }
    float g0 = __shfl(gv, 0), g1 = __shfl(gv, 1), g2 = __shfl(gv, 2), g3 = __shfl(gv, 3);
    if (l == 0) {
      float pi = a0 + g0, pf = a1 + g1, pg = a2 + g2, po = a3 + g3;
      float i_ = 1.f / (1.f + expf(-pi));
      float f_ = 1.f / (1.f + expf(-pf));
      float gg = tanhf(pg);
      float o_ = 1.f / (1.f + expf(-po));
      c = f_ * c + i_ * gg;
      // write-through store: at coherence point once this wave's vmcnt drains
      astoref(&hhist[(size_t)((t + 1) & hmask) * HDIM + bid * 8 + wv], o_ * tanhf(c));
    }
    __syncthreads();  // B3: every wave drained vmcnt(0) before s_barrier
    if (tid == 0) astore(&flags[bid * FLAG_STRIDE], t + 1);
  }
}

// ---------------- heads: two 2048-dots ----------------
__global__ void k_heads(const float* __restrict__ h, const float* __restrict__ wt,
                        const float* __restrict__ bt, const float* __restrict__ wf,
                        const float* __restrict__ bfp, float* __restrict__ out) {
  int tid = threadIdx.x;  // 256
  float st = 0.f, sf = 0.f;
  for (int i = tid; i < HDIM; i += 256) {
    float hv = h[i];
    st += hv * wt[i];
    sf += hv * wf[i];
  }
#pragma unroll
  for (int m = 32; m >= 1; m >>= 1) {
    st += __shfl_xor(st, m, 64);
    sf += __shfl_xor(sf, m, 64);
  }
  __shared__ float ra[4], rb[4];
  if ((tid & 63) == 0) { ra[tid >> 6] = st; rb[tid >> 6] = sf; }
  __syncthreads();
  if (tid == 0) {
    out[0] = ra[0] + ra[1] + ra[2] + ra[3] + bt[0];
    out[1] = rb[0] + rb[1] + rb[2] + rb[3] + bfp[0];
  }
}

// ---------------- launch ----------------
extern "C" void kernel_launch(void* const* d_in, const int* in_sizes, int n_in,
                              void* d_out, int out_size, void* d_ws, size_t ws_size,
                              hipStream_t stream) {
  const float* x     = (const float*)d_in[0];
  const float* w_ih0 = (const float*)d_in[1];
  const float* w_hh0 = (const float*)d_in[2];
  const float* b_ih0 = (const float*)d_in[3];
  const float* b_hh0 = (const float*)d_in[4];
  const float* w_ih1 = (const float*)d_in[5];
  const float* w_hh1 = (const float*)d_in[6];
  const float* b_ih1 = (const float*)d_in[7];
  const float* b_hh1 = (const float*)d_in[8];
  const float* w_t   = (const float*)d_in[9];
  const float* b_t   = (const float*)d_in[10];
  const float* w_f   = (const float*)d_in[11];
  const float* b_f   = (const float*)d_in[12];

  // workspace layout (bytes), total ~236.2 MiB (known-good budget; R5 layout)
  char* p = (char*)d_ws;
  float* gx    = (float*)(p);                 // 134,217,728
  float* hs0f  = (float*)(p + 134217728);     // 4097*2048*4 = 33,562,624
  u16*   xb    = (u16*)  (p + 167780352);     // 4,194,304
  u16*   wb0   = (u16*)  (p + 171974656);     // 8,388,608
  u16*   wb1   = (u16*)  (p + 180363264);     // 33,554,432
  uint4* wprep = (uint4*)(p + 213917696);     // 33,554,432 (reused per layer)
  float* h1r   = (float*)(p + 247472128);     // 4*2048*4 = 32,768 (depth-4 ring)
  float* bias0 = (float*)(p + 247504896);     // 32,768
  float* bias1 = (float*)(p + 247537664);     // 32,768
  int*   flags0= (int*)  (p + 247570432);     // spread [256*32] ints = 32,768
  int*   flags1= (int*)  (p + 247603200);     // spread [256*32] ints = 32,768
  int*   epoch0= (int*)  (p + 247635968);     // 128
  int*   epoch1= (int*)  (p + 247636096);     // 128

  // init (re-run every launch => deterministic graph replay)
  k_zero_f32<<<8, 256, 0, stream>>>(hs0f, HDIM);        // h0 row 0 = 0
  k_zero_f32<<<32, 256, 0, stream>>>(h1r, 4 * HDIM);    // layer-1 ring = 0
  // zero flags0+flags1+epoch0+epoch1 (contiguous region)
  k_zero_f32<<<64, 256, 0, stream>>>((float*)flags0, 2 * NBLK * FLAG_STRIDE + 64);
  k_bias_sum<<<GDIM / 256, 256, 0, stream>>>(b_ih0, b_hh0, bias0, GDIM);
  k_bias_sum<<<GDIM / 256, 256, 0, stream>>>(b_ih1, b_hh1, bias1, GDIM);
  k_cvt_bf16<<<1024, 256, 0, stream>>>(x, xb, T_SEQ * INDIM);
  k_cvt_bf16<<<1024, 256, 0, stream>>>(w_ih0, wb0, GDIM * INDIM);
  k_cvt_bf16<<<2048, 256, 0, stream>>>(w_ih1, wb1, GDIM * HDIM);

  // layer 0
  k_prep_whh<<<NBLK, 512, 0, stream>>>(w_hh0, wprep);
  gemm_bt_bias<false><<<dim3(GDIM / 128, T_SEQ / 128), 256, 0, stream>>>(
      xb, wb0, bias0, gx, T_SEQ, GDIM, INDIM);
  lstm_rec<<<NBLK, 512, 0, stream>>>(gx, wprep, hs0f, flags0, epoch0,
                                     0x7fffffff, T_SEQ);

  // layer 1 (A = hs0 fp32 rows 1..T, converted in GEMM staging)
  gemm_bt_bias<true><<<dim3(GDIM / 128, T_SEQ / 128), 256, 0, stream>>>(
      hs0f + HDIM, wb1, bias1, gx, T_SEQ, GDIM, HDIM);
  k_prep_whh<<<NBLK, 512, 0, stream>>>(w_hh1, wprep);
  lstm_rec<<<NBLK, 512, 0, stream>>>(gx, wprep, h1r, flags1, epoch1, 3, T_SEQ);

  // heads on h1[T] (ring row T&3 == 0)
  k_heads<<<1, 256, 0, stream>>>(h1r + (size_t)(T_SEQ & 3) * HDIM, w_t, b_t, w_f, b_f,
                                 (float*)d_out);
}

// Round 10
// 23510.948 us; speedup vs baseline: 1.9804x; 1.2338x over previous
//
#include <hip/hip_runtime.h>

typedef __attribute__((ext_vector_type(4))) float f32x4;
typedef __attribute__((ext_vector_type(8))) short short8;
typedef __attribute__((ext_vector_type(2))) _Float16 half2v;
typedef unsigned int u32;
typedef unsigned short u16;
typedef unsigned long long u64;

#define T_SEQ 4096
#define HDIM  2048
#define GDIM  8192   // 4*H
#define INDIM 512
#define NBLK  256    // recurrence blocks
#define FLAG_STRIDE 32  // ints -> 128B per flag line (spread; R5-proven)

#if defined(__has_builtin)
#if __has_builtin(__builtin_amdgcn_fdot2)
#define HAS_FDOT2 1
#endif
#if __has_builtin(__builtin_amdgcn_exp2f)
#define EXP2F(x) __builtin_amdgcn_exp2f(x)   // v_exp_f32: 2^x, ~1 ulp
#endif
#endif
#ifndef HAS_FDOT2
#define HAS_FDOT2 0
#endif
#ifndef EXP2F
#define EXP2F(x) exp2f(x)
#endif

__device__ __forceinline__ u16 f2bf(float x) {
  u32 u = __float_as_uint(x);
  return (u16)((u + 0x7fffu + ((u >> 16) & 1u)) >> 16);  // RNE
}
__device__ __forceinline__ u16 f2h(float x) {
  _Float16 h = (_Float16)x;  // RNE
  return __builtin_bit_cast(unsigned short, h);
}
__device__ __forceinline__ float hlo(u32 u) {
  return (float)__builtin_bit_cast(_Float16, (unsigned short)(u & 0xffffu));
}
__device__ __forceinline__ float hhi(u32 u) {
  return (float)__builtin_bit_cast(_Float16, (unsigned short)(u >> 16));
}

// relaxed agent-scope accessors (single sc-bit op to coherence point, no
// invalidate/writeback). RULE (round-6 lesson): spin-polls must be
// same-address-per-wave / few addresses per line device-wide.
__device__ __forceinline__ int aload(const int* p) {
  return __hip_atomic_load(p, __ATOMIC_RELAXED, __HIP_MEMORY_SCOPE_AGENT);
}
__device__ __forceinline__ void astore(int* p, int v) {
  __hip_atomic_store(p, v, __ATOMIC_RELAXED, __HIP_MEMORY_SCOPE_AGENT);
}
__device__ __forceinline__ u64 aload64(const u64* p) {
  return __hip_atomic_load(p, __ATOMIC_RELAXED, __HIP_MEMORY_SCOPE_AGENT);
}
__device__ __forceinline__ void astoref(float* p, float v) {
  __hip_atomic_store(p, v, __ATOMIC_RELAXED, __HIP_MEMORY_SCOPE_AGENT);
}

// ---------------- prep kernels ----------------
__global__ void k_zero_f32(float* __restrict__ p, int n) {
  int i = blockIdx.x * blockDim.x + threadIdx.x;
  int st = gridDim.x * blockDim.x;
  for (; i < n; i += st) p[i] = 0.f;
}

__global__ void k_bias_sum(const float* __restrict__ a, const float* __restrict__ b,
                           float* __restrict__ o, int n) {
  int i = blockIdx.x * blockDim.x + threadIdx.x;
  if (i < n) o[i] = a[i] + b[i];
}

__global__ void k_cvt_bf16(const float* __restrict__ in, u16* __restrict__ out, int n) {
  int i = blockIdx.x * blockDim.x + threadIdx.x;
  int st = gridDim.x * blockDim.x;
  for (; i < n; i += st) out[i] = f2bf(in[i]);
}

// Pre-pack W_hh (fp32 [8192][2048]) into per-block striped f16 layout (R6-proven).
// slot = s*512 + tid: l = slot&63 (lane), r3 = slot>>6, g = r3&3 (k-subgroup),
// q = (r3>>2)&3 (gate), wv = r3>>4 (wave / h-element).
// gate row = q*2048 + bid*8 + wv ; k = l*32 + g*8 .. +8  (8 f16 -> uint4)
__global__ __launch_bounds__(512) void k_prep_whh(const float* __restrict__ w,
                                                  uint4* __restrict__ out) {
  const int bid = blockIdx.x;
  const int tid = threadIdx.x;
#pragma unroll
  for (int s = 0; s < 16; ++s) {
    int slot = s * 512 + tid;
    int l = slot & 63, r3 = slot >> 6;
    int g = r3 & 3, q = (r3 >> 2) & 3, wv = r3 >> 4;
    int grow = q * HDIM + bid * 8 + wv;
    const float* src = w + (size_t)grow * HDIM + l * 32 + g * 8;
    uint4 o;
    o.x = (u32)f2h(src[0]) | ((u32)f2h(src[1]) << 16);
    o.y = (u32)f2h(src[2]) | ((u32)f2h(src[3]) << 16);
    o.z = (u32)f2h(src[4]) | ((u32)f2h(src[5]) << 16);
    o.w = (u32)f2h(src[6]) | ((u32)f2h(src[7]) << 16);
    out[((size_t)bid * 16 + s) * 512 + tid] = o;
  }
}

// ---------------- bf16 MFMA GEMM:  C[M,N] = A[M,K] * B[N,K]^T + bias[N] ----------------
template <bool AF32>
__global__ __launch_bounds__(256) void gemm_bt_bias(
    const void* __restrict__ Av, const u16* __restrict__ B,
    const float* __restrict__ bias, float* __restrict__ C,
    int M, int N, int K)
{
  __shared__ u16 As[128 * 64];
  __shared__ u16 Bs[128 * 64];
  const int tid = threadIdx.x;
  const int m0 = blockIdx.y * 128;
  const int n0 = blockIdx.x * 128;
  const int w = tid >> 6;
  const int lane = tid & 63;
  const int wm = (w >> 1) * 64, wn = (w & 1) * 64;
  const int lr = lane & 15, lk = lane >> 4;

  f32x4 acc[4][4];
  f32x4 zero = {0.f, 0.f, 0.f, 0.f};
#pragma unroll
  for (int i = 0; i < 4; ++i)
#pragma unroll
    for (int j = 0; j < 4; ++j) acc[i][j] = zero;

  const int r = tid >> 1;           // 0..127 (tile row)
  const int sbase = (tid & 1) * 4;  // slot base (each slot = 8 bf16 = 16B)

  for (int kt = 0; kt < K; kt += 64) {
    uint4 va[4], vb[4];
#pragma unroll
    for (int s = 0; s < 4; ++s) {
      if constexpr (AF32) {
        const float* ga = (const float*)Av + (size_t)(m0 + r) * K + kt + (sbase + s) * 8;
        float4 f0 = *reinterpret_cast<const float4*>(ga);
        float4 f1 = *reinterpret_cast<const float4*>(ga + 4);
        va[s].x = (u32)f2bf(f0.x) | ((u32)f2bf(f0.y) << 16);
        va[s].y = (u32)f2bf(f0.z) | ((u32)f2bf(f0.w) << 16);
        va[s].z = (u32)f2bf(f1.x) | ((u32)f2bf(f1.y) << 16);
        va[s].w = (u32)f2bf(f1.z) | ((u32)f2bf(f1.w) << 16);
      } else {
        const u16* ga = (const u16*)Av + (size_t)(m0 + r) * K + kt + (sbase + s) * 8;
        va[s] = *reinterpret_cast<const uint4*>(ga);
      }
      const u16* gb = B + (size_t)(n0 + r) * K + kt + (sbase + s) * 8;
      vb[s] = *reinterpret_cast<const uint4*>(gb);
    }
    __syncthreads();  // previous iter's reads done before overwrite
#pragma unroll
    for (int s = 0; s < 4; ++s) {
      int ps = (sbase + s) ^ (r & 7);
      *reinterpret_cast<uint4*>(&As[r * 64 + ps * 8]) = va[s];
      *reinterpret_cast<uint4*>(&Bs[r * 64 + ps * 8]) = vb[s];
    }
    __syncthreads();
#pragma unroll
    for (int k32 = 0; k32 < 2; ++k32) {
      short8 af[4], bg[4];
#pragma unroll
      for (int i = 0; i < 4; ++i) {
        int arow = wm + i * 16 + lr;
        int aslot = (k32 * 4 + lk) ^ (arow & 7);
        af[i] = *reinterpret_cast<const short8*>(&As[arow * 64 + aslot * 8]);
        int brow = wn + i * 16 + lr;
        int bslot = (k32 * 4 + lk) ^ (brow & 7);
        bg[i] = *reinterpret_cast<const short8*>(&Bs[brow * 64 + bslot * 8]);
      }
#pragma unroll
      for (int i = 0; i < 4; ++i)
#pragma unroll
        for (int j = 0; j < 4; ++j)
          acc[i][j] = __builtin_amdgcn_mfma_f32_16x16x32_bf16(af[i], bg[j], acc[i][j], 0, 0, 0);
    }
  }

  // epilogue: C/D layout col = lane&15, row = (lane>>4)*4 + reg  [m89-verified]
#pragma unroll
  for (int j = 0; j < 4; ++j) {
    int gcol = n0 + wn + j * 16 + lr;
    float bv = bias[gcol];
#pragma unroll
    for (int i = 0; i < 4; ++i) {
      int grow = m0 + wm + i * 16 + lk * 4;
#pragma unroll
      for (int rr = 0; rr < 4; ++rr)
        C[(size_t)(grow + rr) * N + gcol] = acc[i][j][rr] + bv;
    }
  }
}

// ---------------- persistent LSTM recurrence ----------------
// R8 base (proven: 3.5 us/step): weights f16 in LDS + pre-poll reg prefetch,
// fdot2 dot, aload64 h staging, spread flags, write-through h store.
// R10 = R9 fixed to compile: (1) PER-BLOCK hub -- every block's wave0 polls
// all 256 flags directly, removing the epoch publish+detect hop; (2) wave-
// parallel fast gates via __builtin_amdgcn_exp2f (v_exp_f32) -- lanes 0-3
// each compute one activation, shfl gather, all lanes update c.
__global__ __launch_bounds__(512, 1) void lstm_rec(
    const float* __restrict__ gx,    // [T][8192] input contribution (+biases)
    const uint4* __restrict__ wp,    // pre-packed f16 weights [256][16][512]
    float* __restrict__ hhist,       // rows of 2048 floats, row 0 pre-zeroed
    int* __restrict__ flags,         // [NBLK*FLAG_STRIDE] spread, pre-zeroed
    int hmask, int T)
{
  __shared__ uint4 wlds[16 * 512];   // 128 KiB f16 weights
  __shared__ float4 hT[512];         // 8 KiB swizzled h row
  const int tid = threadIdx.x;
  const int bid = blockIdx.x;
  const int wv = tid >> 6;  // wave -> h element bid*8+wv
  const int l = tid & 63;

  // stage weights once (coalesced)
#pragma unroll
  for (int s = 0; s < 16; ++s)
    wlds[s * 512 + tid] = wp[((size_t)bid * 16 + s) * 512 + tid];
  __syncthreads();  // B0: wlds complete before the pre-poll prefetch reads it

  float c = 0.f;  // cell state (all lanes of each wave, kept consistent)

  for (int t = 0; t < T; ++t) {
    // weight prefetch into registers (overlaps the poll; R2-proven scalar pins)
    uint4 wr[16];
#pragma unroll
    for (int s = 0; s < 16; ++s) wr[s] = wlds[(wv * 16 + s) * 64 + l];
#pragma unroll
    for (int s = 0; s < 16; ++s)
      asm volatile("" : "+v"(wr[s].x), "+v"(wr[s].y), "+v"(wr[s].z), "+v"(wr[s].w));

    // gx prefetch (cached load, independent of h[t]; overlaps the poll)
    float gv = 0.f;
    if (l < 4) gv = gx[(size_t)t * GDIM + l * HDIM + bid * 8 + wv];

    // ---- wait for h[t]: per-block hub (wave0 polls all 256 flags, 4/lane) ----
    if (wv == 0) {
      const int* f0 = &flags[(l * 4 + 0) * FLAG_STRIDE];
      const int* f1 = &flags[(l * 4 + 1) * FLAG_STRIDE];
      const int* f2 = &flags[(l * 4 + 2) * FLAG_STRIDE];
      const int* f3 = &flags[(l * 4 + 3) * FLAG_STRIDE];
      while (true) {
        int m0 = min(min(aload(f0), aload(f1)), min(aload(f2), aload(f3)));
        if (__all(m0 >= t)) break;
        __builtin_amdgcn_s_sleep(1);
      }
    }
    __syncthreads();  // B1: h[t] globally ready

    // stage h[t] into LDS (relaxed-agent 8B loads -> coherence point, fresh)
    {
      const u64* hsrc = (const u64*)(hhist + (size_t)(t & hmask) * HDIM);
      u64 d0 = aload64(&hsrc[tid * 2]);
      u64 d1 = aload64(&hsrc[tid * 2 + 1]);
      float4 hv;
      hv.x = __uint_as_float((u32)d0);
      hv.y = __uint_as_float((u32)(d0 >> 32));
      hv.z = __uint_as_float((u32)d1);
      hv.w = __uint_as_float((u32)(d1 >> 32));
      int G2 = tid & 7, sb = tid >> 3;
      hT[G2 * 64 + (sb ^ ((G2 * 9) & 63))] = hv;
    }
    __syncthreads();  // B2: h staged

    // dot: 8 hT reads + fdot2 against prefetched weights
    float a0 = 0.f, a1 = 0.f, a2 = 0.f, a3 = 0.f;
#pragma unroll
    for (int g = 0; g < 4; ++g) {
      const int G0 = g * 2, G1 = g * 2 + 1;
      float4 h0 = hT[G0 * 64 + (l ^ ((G0 * 9) & 63))];
      float4 h1 = hT[G1 * 64 + (l ^ ((G1 * 9) & 63))];
#if HAS_FDOT2
      half2v p0, p1, p2, p3;
      p0[0] = (_Float16)h0.x; p0[1] = (_Float16)h0.y;
      p1[0] = (_Float16)h0.z; p1[1] = (_Float16)h0.w;
      p2[0] = (_Float16)h1.x; p2[1] = (_Float16)h1.y;
      p3[0] = (_Float16)h1.z; p3[1] = (_Float16)h1.w;
#define FD2(wu, pp, acc) __builtin_amdgcn_fdot2(__builtin_bit_cast(half2v, (wu)), (pp), (acc), false)
      a0 = FD2(wr[0 + g].x, p0, FD2(wr[0 + g].y, p1, FD2(wr[0 + g].z, p2, FD2(wr[0 + g].w, p3, a0))));
      a1 = FD2(wr[4 + g].x, p0, FD2(wr[4 + g].y, p1, FD2(wr[4 + g].z, p2, FD2(wr[4 + g].w, p3, a1))));
      a2 = FD2(wr[8 + g].x, p0, FD2(wr[8 + g].y, p1, FD2(wr[8 + g].z, p2, FD2(wr[8 + g].w, p3, a2))));
      a3 = FD2(wr[12 + g].x, p0, FD2(wr[12 + g].y, p1, FD2(wr[12 + g].z, p2, FD2(wr[12 + g].w, p3, a3))));
#undef FD2
#else
      a0 += hlo(wr[0 + g].x) * h0.x + hhi(wr[0 + g].x) * h0.y + hlo(wr[0 + g].y) * h0.z + hhi(wr[0 + g].y) * h0.w +
            hlo(wr[0 + g].z) * h1.x + hhi(wr[0 + g].z) * h1.y + hlo(wr[0 + g].w) * h1.z + hhi(wr[0 + g].w) * h1.w;
      a1 += hlo(wr[4 + g].x) * h0.x + hhi(wr[4 + g].x) * h0.y + hlo(wr[4 + g].y) * h0.z + hhi(wr[4 + g].y) * h0.w +
            hlo(wr[4 + g].z) * h1.x + hhi(wr[4 + g].z) * h1.y + hlo(wr[4 + g].w) * h1.z + hhi(wr[4 + g].w) * h1.w;
      a2 += hlo(wr[8 + g].x) * h0.x + hhi(wr[8 + g].x) * h0.y + hlo(wr[8 + g].y) * h0.z + hhi(wr[8 + g].y) * h0.w +
            hlo(wr[8 + g].z) * h1.x + hhi(wr[8 + g].z) * h1.y + hlo(wr[8 + g].w) * h1.z + hhi(wr[8 + g].w) * h1.w;
      a3 += hlo(wr[12 + g].x) * h0.x + hhi(wr[12 + g].x) * h0.y + hlo(wr[12 + g].y) * h0.z + hhi(wr[12 + g].y) * h0.w +
            hlo(wr[12 + g].z) * h1.x + hhi(wr[12 + g].z) * h1.y + hlo(wr[12 + g].w) * h1.z + hhi(wr[12 + g].w) * h1.w;
#endif
    }
    // 64-lane butterfly: all lanes end with the 4 gate sums
#pragma unroll
    for (int m = 32; m >= 1; m >>= 1) {
      a0 += __shfl_xor(a0, m);
      a1 += __shfl_xor(a1, m);
      a2 += __shfl_xor(a2, m);
      a3 += __shfl_xor(a3, m);
    }
    float g0 = __shfl(gv, 0), g1 = __shfl(gv, 1), g2 = __shfl(gv, 2), g3 = __shfl(gv, 3);

    // wave-parallel gates: lane0->i (sigmoid), lane1->f (sigmoid),
    // lane2->g (tanh), lane3->o (sigmoid); single v_exp_f32 per lane.
    // sigmoid(x) = 1/(1+exp2(-x*log2e)); tanh(x) = 1 - 2/(exp2(2x*log2e)+1)
    {
      const float L2E = 1.44269504f;
      float pre = (l & 2) ? ((l & 1) ? a3 + g3 : a2 + g2)
                          : ((l & 1) ? a1 + g1 : a0 + g0);
      float k = (l == 2) ? 2.f * L2E : -L2E;
      float e = EXP2F(k * pre);
      float act = (l == 2) ? (1.f - 2.f / (e + 1.f)) : (1.f / (1.f + e));
      float i_ = __shfl(act, 0);
      float f_ = __shfl(act, 1);
      float gg = __shfl(act, 2);
      float o_ = __shfl(act, 3);
      c = f_ * c + i_ * gg;  // all lanes redundantly (consistent arithmetic)
      float th = 1.f - 2.f / (EXP2F(2.f * L2E * c) + 1.f);
      float hval = o_ * th;
      if (l == 0) {
        // write-through store: at coherence point once this wave's vmcnt drains
        astoref(&hhist[(size_t)((t + 1) & hmask) * HDIM + bid * 8 + wv], hval);
      }
    }
    __syncthreads();  // B3: every wave drained vmcnt(0) before s_barrier
    if (tid == 0) astore(&flags[bid * FLAG_STRIDE], t + 1);
  }
}

// ---------------- heads: two 2048-dots ----------------
__global__ void k_heads(const float* __restrict__ h, const float* __restrict__ wt,
                        const float* __restrict__ bt, const float* __restrict__ wf,
                        const float* __restrict__ bfp, float* __restrict__ out) {
  int tid = threadIdx.x;  // 256
  float st = 0.f, sf = 0.f;
  for (int i = tid; i < HDIM; i += 256) {
    float hv = h[i];
    st += hv * wt[i];
    sf += hv * wf[i];
  }
#pragma unroll
  for (int m = 32; m >= 1; m >>= 1) {
    st += __shfl_xor(st, m, 64);
    sf += __shfl_xor(sf, m, 64);
  }
  __shared__ float ra[4], rb[4];
  if ((tid & 63) == 0) { ra[tid >> 6] = st; rb[tid >> 6] = sf; }
  __syncthreads();
  if (tid == 0) {
    out[0] = ra[0] + ra[1] + ra[2] + ra[3] + bt[0];
    out[1] = rb[0] + rb[1] + rb[2] + rb[3] + bfp[0];
  }
}

// ---------------- launch ----------------
extern "C" void kernel_launch(void* const* d_in, const int* in_sizes, int n_in,
                              void* d_out, int out_size, void* d_ws, size_t ws_size,
                              hipStream_t stream) {
  const float* x     = (const float*)d_in[0];
  const float* w_ih0 = (const float*)d_in[1];
  const float* w_hh0 = (const float*)d_in[2];
  const float* b_ih0 = (const float*)d_in[3];
  const float* b_hh0 = (const float*)d_in[4];
  const float* w_ih1 = (const float*)d_in[5];
  const float* w_hh1 = (const float*)d_in[6];
  const float* b_ih1 = (const float*)d_in[7];
  const float* b_hh1 = (const float*)d_in[8];
  const float* w_t   = (const float*)d_in[9];
  const float* b_t   = (const float*)d_in[10];
  const float* w_f   = (const float*)d_in[11];
  const float* b_f   = (const float*)d_in[12];

  // workspace layout (bytes), total ~236.2 MiB (known-good budget; R5 layout)
  char* p = (char*)d_ws;
  float* gx    = (float*)(p);                 // 134,217,728
  float* hs0f  = (float*)(p + 134217728);     // 4097*2048*4 = 33,562,624
  u16*   xb    = (u16*)  (p + 167780352);     // 4,194,304
  u16*   wb0   = (u16*)  (p + 171974656);     // 8,388,608
  u16*   wb1   = (u16*)  (p + 180363264);     // 33,554,432
  uint4* wprep = (uint4*)(p + 213917696);     // 33,554,432 (reused per layer)
  float* h1r   = (float*)(p + 247472128);     // 4*2048*4 = 32,768 (depth-4 ring)
  float* bias0 = (float*)(p + 247504896);     // 32,768
  float* bias1 = (float*)(p + 247537664);     // 32,768
  int*   flags0= (int*)  (p + 247570432);     // spread [256*32] ints = 32,768
  int*   flags1= (int*)  (p + 247603200);     // spread [256*32] ints = 32,768

  // init (re-run every launch => deterministic graph replay)
  k_zero_f32<<<8, 256, 0, stream>>>(hs0f, HDIM);        // h0 row 0 = 0
  k_zero_f32<<<32, 256, 0, stream>>>(h1r, 4 * HDIM);    // layer-1 ring = 0
  k_zero_f32<<<64, 256, 0, stream>>>((float*)flags0, 2 * NBLK * FLAG_STRIDE);
  k_bias_sum<<<GDIM / 256, 256, 0, stream>>>(b_ih0, b_hh0, bias0, GDIM);
  k_bias_sum<<<GDIM / 256, 256, 0, stream>>>(b_ih1, b_hh1, bias1, GDIM);
  k_cvt_bf16<<<1024, 256, 0, stream>>>(x, xb, T_SEQ * INDIM);
  k_cvt_bf16<<<1024, 256, 0, stream>>>(w_ih0, wb0, GDIM * INDIM);
  k_cvt_bf16<<<2048, 256, 0, stream>>>(w_ih1, wb1, GDIM * HDIM);

  // layer 0
  k_prep_whh<<<NBLK, 512, 0, stream>>>(w_hh0, wprep);
  gemm_bt_bias<false><<<dim3(GDIM / 128, T_SEQ / 128), 256, 0, stream>>>(
      xb, wb0, bias0, gx, T_SEQ, GDIM, INDIM);
  lstm_rec<<<NBLK, 512, 0, stream>>>(gx, wprep, hs0f, flags0, 0x7fffffff, T_SEQ);

  // layer 1 (A = hs0 fp32 rows 1..T, converted in GEMM staging)
  gemm_bt_bias<true><<<dim3(GDIM / 128, T_SEQ / 128), 256, 0, stream>>>(
      hs0f + HDIM, wb1, bias1, gx, T_SEQ, GDIM, HDIM);
  k_prep_whh<<<NBLK, 512, 0, stream>>>(w_hh1, wprep);
  lstm_rec<<<NBLK, 512, 0, stream>>>(gx, wprep, h1r, flags1, 3, T_SEQ);

  // heads on h1[T] (ring row T&3 == 0)
  k_heads<<<1, 256, 0, stream>>>(h1r + (size_t)(T_SEQ & 3) * HDIM, w_t, b_t, w_f, b_f,
                                 (float*)d_out);
}